// Round 3
// baseline (535.605 us; speedup 1.0000x reference)
//
#include <hip/hip_runtime.h>
#include <math.h>

#define GHH 224
#define GWW 224
#define HW (GHH*GWW)     // 50176
#define BATCH 8
#define RAD 3
#define DIAM 7
#define NPTS 49
#define QC 32
#define TILE 16
#define TP (TILE + 2*RAD)   // 22
#define TPIX (TP*TP)        // 484

__device__ __forceinline__ int refl(int i) {
    // jnp.pad mode='reflect', pad=3, N=224
    if (i < 0) i = -i;
    if (i >= GHH) i = 2*GHH - 2 - i;
    return i;
}

// ---------------- linear: f0[b][j] = x[b] . W[j] + bias[j] ----------------
__global__ void linear_kernel(const float* __restrict__ x,
                              const float* __restrict__ W,
                              const float* __restrict__ bias,
                              float* __restrict__ f0) {
    int gwave = (blockIdx.x * blockDim.x + threadIdx.x) >> 6;
    int lane = threadIdx.x & 63;
    if (gwave >= BATCH * 972) return;
    int b = gwave / 972, j = gwave % 972;
    const float* xr = x + b * 1000;
    const float* wr = W + j * 1000;
    float s = 0.f;
    for (int k = lane; k < 1000; k += 64)
        s += xr[k] * wr[k];
    #pragma unroll
    for (int off = 32; off; off >>= 1) s += __shfl_down(s, off, 64);
    if (lane == 0) f0[gwave] = s + bias[j];
}

// ---------------- bicubic 18 -> 224 (torch bicubic, a=-0.75, border clamp) ----------------
__device__ __forceinline__ float cubicw(float d) {
    d = fabsf(d);
    if (d <= 1.f) return ((1.25f * d - 2.25f) * d) * d + 1.f;
    if (d < 2.f)  return ((-0.75f * d + 3.75f) * d - 6.f) * d + 3.f;
    return 0.f;
}

__global__ void bicubic_kernel(const float* __restrict__ f0, float* __restrict__ hr) {
    int idx = blockIdx.x * blockDim.x + threadIdx.x;
    if (idx >= BATCH * 3 * HW) return;
    int w = idx % GWW;
    int h = (idx / GWW) % GHH;
    int bc = idx / HW;
    const float* src = f0 + bc * 18 * 18;
    float xx = (w + 0.5f) * (18.f / 224.f) - 0.5f;
    float yy = (h + 0.5f) * (18.f / 224.f) - 0.5f;
    float fx0 = floorf(xx), fy0 = floorf(yy);
    int x0 = (int)fx0, y0 = (int)fy0;
    float tx = xx - fx0, ty = yy - fy0;
    float wx[4], wy[4];
    int ix[4], iy[4];
    #pragma unroll
    for (int k = 0; k < 4; k++) {
        wx[k] = cubicw(tx - (float)(k - 1));
        wy[k] = cubicw(ty - (float)(k - 1));
        int a = x0 + (k - 1); ix[k] = min(max(a, 0), 17);
        a = y0 + (k - 1);     iy[k] = min(max(a, 0), 17);
    }
    float acc = 0.f;
    #pragma unroll
    for (int ky = 0; ky < 4; ky++) {
        float rowv = 0.f;
        #pragma unroll
        for (int kx = 0; kx < 4; kx++) rowv += wx[kx] * src[iy[ky] * 18 + ix[kx]];
        acc += wy[ky] * rowv;
    }
    hr[idx] = acc;
}

// ---------------- range_proj: q = W2 . gelu(W1 . guidance + b1) + b2, channel-last f32 ----------------
__global__ void rangeproj_kernel(const float* __restrict__ guid,
                                 const float* __restrict__ w1,
                                 const float* __restrict__ b1,
                                 const float* __restrict__ w2,
                                 const float* __restrict__ b2,
                                 float* __restrict__ q) {
    __shared__ float sw1[QC * 3], sb1[QC], sw2[QC * QC], sb2[QC];
    int tid = threadIdx.x;
    for (int i = tid; i < QC * 3; i += 256) sw1[i] = w1[i];
    if (tid < QC) { sb1[tid] = b1[tid]; sb2[tid] = b2[tid]; }
    for (int i = tid; i < QC * QC; i += 256) sw2[i] = w2[i];
    __syncthreads();
    int idx = blockIdx.x * 256 + tid;
    if (idx >= BATCH * HW) return;
    int b = idx / HW, pix = idx % HW;
    float g0 = guid[(b * 3 + 0) * HW + pix];
    float g1 = guid[(b * 3 + 1) * HW + pix];
    float g2 = guid[(b * 3 + 2) * HW + pix];
    float h1[QC];
    #pragma unroll
    for (int k = 0; k < QC; k++) {
        float v = sw1[k * 3] * g0 + sw1[k * 3 + 1] * g1 + sw1[k * 3 + 2] * g2 + sb1[k];
        h1[k] = 0.5f * v * (1.f + erff(v * 0.70710678118654752f));  // exact GELU
    }
    float* qout = q + (size_t)idx * QC;
    #pragma unroll
    for (int k = 0; k < QC; k++) {
        float acc = sb2[k];
        #pragma unroll
        for (int c = 0; c < QC; c++) acc += sw2[k * QC + c] * h1[c];
        qout[k] = acc;
    }
}

// ---------------- fused JBU: scores -> softmax*spatial -> renorm -> adaptive 7x7 conv ----------------
__global__ __launch_bounds__(256) void jbu_kernel(
    const float* __restrict__ q,
    const float* __restrict__ hr,
    float* __restrict__ outF,
    const float* __restrict__ temps,
    const float* __restrict__ sigmas,
    int stage)
{
    __shared__ __align__(16) float lds[2 * TPIX * 4];  // 15488 B; reused for hr tile (needs 1452 f)
    int tx = threadIdx.x, ty = threadIdx.y;
    int tid = ty * TILE + tx;
    int b = blockIdx.z;
    int h0 = blockIdx.y * TILE, w0 = blockIdx.x * TILE;

    float s[NPTS];
    #pragma unroll
    for (int p = 0; p < NPTS; p++) s[p] = 0.f;

    // ---- scores over 4 chunks of 8 channels ----
    for (int cc = 0; cc < 4; cc++) {
        __syncthreads();
        for (int i = tid; i < TPIX; i += 256) {
            int r = i / TP, c = i % TP;
            int gh = refl(h0 - RAD + r);
            int gw = refl(w0 - RAD + c);
            const float* src = q + ((size_t)(b * HW + gh * GWW + gw)) * QC + cc * 8;
            float4 a0 = *(const float4*)src;
            float4 a1 = *(const float4*)(src + 4);
            *(float4*)&lds[i * 4] = a0;
            *(float4*)&lds[TPIX * 4 + i * 4] = a1;
        }
        __syncthreads();
        int ci = (ty + RAD) * TP + tx + RAD;
        float4 c0 = *(float4*)&lds[ci * 4];
        float4 c1 = *(float4*)&lds[TPIX * 4 + ci * 4];
        #pragma unroll
        for (int p = 0; p < NPTS; p++) {
            int di = p / 7, dj = p % 7;
            int ni = (ty + di) * TP + tx + dj;
            float4 n0 = *(float4*)&lds[ni * 4];
            float4 n1 = *(float4*)&lds[TPIX * 4 + ni * 4];
            s[p] += c0.x * n0.x + c0.y * n0.y + c0.z * n0.z + c0.w * n0.w
                  + c1.x * n1.x + c1.y * n1.y + c1.z * n1.z + c1.w * n1.w;
        }
    }

    // ---- softmax * spatial, renormalize ----
    float t = __expf(temps[stage]);
    t = fminf(fmaxf(t, 1e-4f), 1e4f);
    float sig = sigmas[stage];
    float inv2s2 = 1.f / (2.f * sig * sig);
    float m = -1e30f;
    #pragma unroll
    for (int p = 0; p < NPTS; p++) { s[p] *= t; m = fmaxf(m, s[p]); }
    float den = 0.f;
    #pragma unroll
    for (int p = 0; p < NPTS; p++) { s[p] = __expf(s[p] - m); den += s[p]; }
    float rden = 1.f / den;
    float ksum = 0.f;
    #pragma unroll
    for (int p = 0; p < NPTS; p++) {
        int di = p / 7, dj = p % 7;
        float dy = (float)(di - 3) * (1.f / 3.f);
        float dx = (float)(dj - 3) * (1.f / 3.f);
        float spat = __expf(-(dy * dy + dx * dx) * inv2s2);
        s[p] = s[p] * rden * spat;
        ksum += s[p];
    }
    float rk = 1.f / fmaxf(ksum, 1e-7f);

    // ---- adaptive conv over hr (3 channels) ----
    __syncthreads();
    for (int i = tid; i < 3 * TPIX; i += 256) {
        int c = i / TPIX, rc = i % TPIX;
        int r = rc / TP, cx = rc % TP;
        int gh = refl(h0 - RAD + r);
        int gw = refl(w0 - RAD + cx);
        lds[i] = hr[(size_t)(b * 3 + c) * HW + gh * GWW + gw];
    }
    __syncthreads();
    float o0 = 0.f, o1 = 0.f, o2 = 0.f;
    #pragma unroll
    for (int p = 0; p < NPTS; p++) {
        int di = p / 7, dj = p % 7;
        int ni = (ty + di) * TP + tx + dj;
        float kp = s[p] * rk;
        o0 += kp * lds[ni];
        o1 += kp * lds[TPIX + ni];
        o2 += kp * lds[2 * TPIX + ni];
    }
    size_t obase = (size_t)b * 3 * HW + (size_t)(h0 + ty) * GWW + (w0 + tx);
    outF[obase]          = o0;
    outF[obase + HW]     = o1;
    outF[obase + 2 * HW] = o2;
}

extern "C" void kernel_launch(void* const* d_in, const int* in_sizes, int n_in,
                              void* d_out, int out_size, void* d_ws, size_t ws_size,
                              hipStream_t stream) {
    const float* x      = (const float*)d_in[0];
    const float* guid   = (const float*)d_in[1];
    const float* lw     = (const float*)d_in[2];
    const float* lb     = (const float*)d_in[3];
    const float* w1s    = (const float*)d_in[4];
    const float* b1s    = (const float*)d_in[5];
    const float* w2s    = (const float*)d_in[6];
    const float* b2s    = (const float*)d_in[7];
    const float* temps  = (const float*)d_in[8];
    const float* sigmas = (const float*)d_in[9];

    char* ws = (char*)d_ws;
    const size_t Q_BYTES  = (size_t)BATCH * HW * QC * sizeof(float);   // 51,380,224
    const size_t F_BYTES  = (size_t)BATCH * 3 * HW * sizeof(float);    //  4,816,896
    float* q   = (float*)ws;
    float* hrA = (float*)(ws + Q_BYTES);
    float* hrB = (float*)(ws + Q_BYTES + F_BYTES);
    float* f0  = (float*)(ws + Q_BYTES + 2 * F_BYTES);                 // 31,104 B

    linear_kernel<<<1944, 256, 0, stream>>>(x, lw, lb, f0);
    bicubic_kernel<<<(BATCH * 3 * HW + 255) / 256, 256, 0, stream>>>(f0, hrA);

    dim3 jgrid(14, 14, BATCH), jblock(TILE, TILE);
    const float* hins[4]  = { hrA, hrB, hrA, hrB };
    float*       fouts[4] = { hrB, hrA, hrB, (float*)d_out };
    for (int s = 0; s < 4; s++) {
        rangeproj_kernel<<<(BATCH * HW + 255) / 256, 256, 0, stream>>>(
            guid, w1s + s * 96, b1s + s * 32, w2s + s * 1024, b2s + s * 32, q);
        jbu_kernel<<<jgrid, jblock, 0, stream>>>(
            q, hins[s], fouts[s], temps, sigmas, s);
    }
}

// Round 4
// 422.051 us; speedup vs baseline: 1.2691x; 1.2691x over previous
//
#include <hip/hip_runtime.h>
#include <hip/hip_fp16.h>
#include <math.h>

#define GHH 224
#define GWW 224
#define HW (GHH*GWW)     // 50176
#define BATCH 8
#define RAD 3
#define DIAM 7
#define NPTS 49
#define QC 32
#define TILE 16
#define TP (TILE + 2*RAD)   // 22
#define TPIX (TP*TP)        // 484

typedef _Float16 h2 __attribute__((ext_vector_type(2)));

#if defined(__has_builtin)
#if __has_builtin(__builtin_amdgcn_fdot2)
#define HAS_FDOT2 1
#endif
#endif

__device__ __forceinline__ h2 as_h2(float f) { union { float f; h2 h; } u; u.f = f; return u.h; }

__device__ __forceinline__ float dot2acc(float a, float b, float acc) {
#ifdef HAS_FDOT2
    return __builtin_amdgcn_fdot2(as_h2(a), as_h2(b), acc, false);
#else
    union { float f; __half2 h; } ua, ub; ua.f = a; ub.f = b;
    float2 fa = __half22float2(ua.h), fb = __half22float2(ub.h);
    return acc + fa.x * fb.x + fa.y * fb.y;
#endif
}

__device__ __forceinline__ float dot16(const float4& a, const float4& b, float acc) {
    acc = dot2acc(a.x, b.x, acc);
    acc = dot2acc(a.y, b.y, acc);
    acc = dot2acc(a.z, b.z, acc);
    acc = dot2acc(a.w, b.w, acc);
    return acc;
}

__device__ __forceinline__ int refl(int i) {
    if (i < 0) i = -i;
    if (i >= GHH) i = 2 * GHH - 2 - i;
    return i;
}

__device__ __forceinline__ float gelu_fast(float v) {
    // tanh-approx GELU; |err| < ~1e-3 abs, our |v| <~ 1 so ~1e-4
    float u = 0.7978845608f * v * (1.f + 0.044715f * v * v);
    float e = __expf(2.f * u);
    float th = 1.f - 2.f / (e + 1.f);
    return 0.5f * v * (1.f + th);
}

// ---------------- linear: f0[b][j] = x[b] . W[j] + bias[j] ----------------
__global__ void linear_kernel(const float* __restrict__ x,
                              const float* __restrict__ W,
                              const float* __restrict__ bias,
                              float* __restrict__ f0) {
    int gwave = (blockIdx.x * blockDim.x + threadIdx.x) >> 6;
    int lane = threadIdx.x & 63;
    if (gwave >= BATCH * 972) return;
    int b = gwave / 972, j = gwave % 972;
    const float* xr = x + b * 1000;
    const float* wr = W + j * 1000;
    float s = 0.f;
    for (int k = lane; k < 1000; k += 64)
        s += xr[k] * wr[k];
    #pragma unroll
    for (int off = 32; off; off >>= 1) s += __shfl_down(s, off, 64);
    if (lane == 0) f0[gwave] = s + bias[j];
}

// ---------------- bicubic 18 -> 224 ----------------
__device__ __forceinline__ float cubicw(float d) {
    d = fabsf(d);
    if (d <= 1.f) return ((1.25f * d - 2.25f) * d) * d + 1.f;
    if (d < 2.f)  return ((-0.75f * d + 3.75f) * d - 6.f) * d + 3.f;
    return 0.f;
}

__global__ void bicubic_kernel(const float* __restrict__ f0, float* __restrict__ hr) {
    int idx = blockIdx.x * blockDim.x + threadIdx.x;
    if (idx >= BATCH * 3 * HW) return;
    int w = idx % GWW;
    int h = (idx / GWW) % GHH;
    int bc = idx / HW;
    const float* src = f0 + bc * 18 * 18;
    float xx = (w + 0.5f) * (18.f / 224.f) - 0.5f;
    float yy = (h + 0.5f) * (18.f / 224.f) - 0.5f;
    float fx0 = floorf(xx), fy0 = floorf(yy);
    int x0 = (int)fx0, y0 = (int)fy0;
    float tx = xx - fx0, ty = yy - fy0;
    float wx[4], wy[4];
    int ix[4], iy[4];
    #pragma unroll
    for (int k = 0; k < 4; k++) {
        wx[k] = cubicw(tx - (float)(k - 1));
        wy[k] = cubicw(ty - (float)(k - 1));
        int a = x0 + (k - 1); ix[k] = min(max(a, 0), 17);
        a = y0 + (k - 1);     iy[k] = min(max(a, 0), 17);
    }
    float acc = 0.f;
    #pragma unroll
    for (int ky = 0; ky < 4; ky++) {
        float rowv = 0.f;
        #pragma unroll
        for (int kx = 0; kx < 4; kx++) rowv += wx[kx] * src[iy[ky] * 18 + ix[kx]];
        acc += wy[ky] * rowv;
    }
    hr[idx] = acc;
}

// ---------------- range_proj -> f16 q, layout [b*HW][4]float4 (8 halves each) ----------------
__global__ __launch_bounds__(256) void rangeproj_kernel(
    const float* __restrict__ guid,
    const float* __restrict__ w1, const float* __restrict__ b1,
    const float* __restrict__ w2, const float* __restrict__ b2,
    float4* __restrict__ q4) {
    __shared__ float sw1[QC * 3], sb1[QC], sw2[QC * QC], sb2[QC];
    __shared__ __align__(16) float4 sout[256 * 5];  // 80B row stride: 4 used + 1 pad float4
    int tid = threadIdx.x;
    for (int i = tid; i < QC * 3; i += 256) sw1[i] = w1[i];
    if (tid < QC) { sb1[tid] = b1[tid]; sb2[tid] = b2[tid]; }
    for (int i = tid; i < QC * QC; i += 256) sw2[i] = w2[i];
    __syncthreads();
    int idx = blockIdx.x * 256 + tid;           // grid sized exactly BATCH*HW/256
    int b = idx / HW, pix = idx % HW;
    float g0 = guid[(b * 3 + 0) * HW + pix];
    float g1 = guid[(b * 3 + 1) * HW + pix];
    float g2 = guid[(b * 3 + 2) * HW + pix];
    float h1[QC];
    #pragma unroll
    for (int k = 0; k < QC; k++) {
        float v = sw1[k * 3] * g0 + sw1[k * 3 + 1] * g1 + sw1[k * 3 + 2] * g2 + sb1[k];
        h1[k] = gelu_fast(v);
    }
    float4 packv[4];
    float* packf = (float*)packv;
    #pragma unroll
    for (int k = 0; k < QC; k += 2) {
        float a0 = sb2[k], a1 = sb2[k + 1];
        #pragma unroll
        for (int c = 0; c < QC; c++) {
            a0 += sw2[k * QC + c] * h1[c];
            a1 += sw2[(k + 1) * QC + c] * h1[c];
        }
        union { __half2 h; float f; } u;
        u.h = __floats2half2_rn(a0, a1);
        packf[k >> 1] = u.f;
    }
    #pragma unroll
    for (int j = 0; j < 4; j++) sout[tid * 5 + j] = packv[j];
    __syncthreads();
    size_t gbase = (size_t)blockIdx.x * 1024;
    #pragma unroll
    for (int k2 = 0; k2 < 4; k2++) {
        int t = k2 * 256 + tid;
        q4[gbase + t] = sout[(t >> 2) * 5 + (t & 3)];
    }
}

// ---------------- fused JBU ----------------
__global__ __launch_bounds__(256, 4) void jbu_kernel(
    const float4* __restrict__ q4,
    const float* __restrict__ hr,
    float* __restrict__ outF,
    const float* __restrict__ temps,
    const float* __restrict__ sigmas,
    int stage)
{
    __shared__ __align__(16) float4 sq[4 * TPIX];  // 30976 B; reused for hr tile (TPIX float4)
    int tx = threadIdx.x, ty = threadIdx.y;
    int tid = ty * TILE + tx;
    int b = blockIdx.z;
    int h0 = blockIdx.y * TILE, w0 = blockIdx.x * TILE;

    // ---- stage all 32 f16 channels, chunk-planar ----
    for (int i = tid; i < 4 * TPIX; i += 256) {
        int px = i >> 2, c = i & 3;
        int r = px / TP, cc = px % TP;
        int gh = refl(h0 - RAD + r);
        int gw = refl(w0 - RAD + cc);
        sq[c * TPIX + px] = q4[(size_t)(b * HW + gh * GWW + gw) * 4 + c];
    }
    __syncthreads();

    int ci = (ty + RAD) * TP + tx + RAD;
    float4 c0 = sq[ci], c1 = sq[TPIX + ci], c2 = sq[2 * TPIX + ci], c3 = sq[3 * TPIX + ci];

    float s[NPTS];
    int p = 0;
    #pragma unroll
    for (int di = 0; di < DIAM; di++) {
        int rb = (ty + di) * TP + tx;
        #pragma unroll
        for (int dj = 0; dj < DIAM; dj++, p++) {
            int ni = rb + dj;
            float acc = dot16(c0, sq[ni], 0.f);
            acc = dot16(c1, sq[TPIX + ni], acc);
            acc = dot16(c2, sq[2 * TPIX + ni], acc);
            acc = dot16(c3, sq[3 * TPIX + ni], acc);
            s[p] = acc;
        }
    }

    // ---- softmax * spatial, renormalize ----
    float t = __expf(temps[stage]);
    t = fminf(fmaxf(t, 1e-4f), 1e4f);
    float sig = sigmas[stage];
    float inv2s2 = 1.f / (2.f * sig * sig);
    float m = -1e30f;
    #pragma unroll
    for (int p2 = 0; p2 < NPTS; p2++) { s[p2] *= t; m = fmaxf(m, s[p2]); }
    float den = 0.f;
    #pragma unroll
    for (int p2 = 0; p2 < NPTS; p2++) { s[p2] = __expf(s[p2] - m); den += s[p2]; }
    float rden = 1.f / den;
    float ksum = 0.f;
    #pragma unroll
    for (int p2 = 0; p2 < NPTS; p2++) {
        int di = p2 / 7, dj = p2 % 7;
        float dy = (float)(di - 3) * (1.f / 3.f);
        float dx = (float)(dj - 3) * (1.f / 3.f);
        float spat = __expf(-(dy * dy + dx * dx) * inv2s2);
        s[p2] = s[p2] * rden * spat;
        ksum += s[p2];
    }
    float rk = 1.f / fmaxf(ksum, 1e-7f);

    // ---- stage hr tile as float4 (3ch + pad) ----
    __syncthreads();
    for (int i = tid; i < TPIX; i += 256) {
        int r = i / TP, cx = i % TP;
        int gh = refl(h0 - RAD + r);
        int gw = refl(w0 - RAD + cx);
        size_t base = (size_t)b * 3 * HW + (size_t)gh * GWW + gw;
        sq[i] = make_float4(hr[base], hr[base + HW], hr[base + 2 * HW], 0.f);
    }
    __syncthreads();

    float o0 = 0.f, o1 = 0.f, o2 = 0.f;
    p = 0;
    #pragma unroll
    for (int di = 0; di < DIAM; di++) {
        int rb = (ty + di) * TP + tx;
        #pragma unroll
        for (int dj = 0; dj < DIAM; dj++, p++) {
            float4 hv = sq[rb + dj];
            float kp = s[p] * rk;
            o0 += kp * hv.x;
            o1 += kp * hv.y;
            o2 += kp * hv.z;
        }
    }
    size_t obase = (size_t)b * 3 * HW + (size_t)(h0 + ty) * GWW + (w0 + tx);
    outF[obase]          = o0;
    outF[obase + HW]     = o1;
    outF[obase + 2 * HW] = o2;
}

extern "C" void kernel_launch(void* const* d_in, const int* in_sizes, int n_in,
                              void* d_out, int out_size, void* d_ws, size_t ws_size,
                              hipStream_t stream) {
    const float* x      = (const float*)d_in[0];
    const float* guid   = (const float*)d_in[1];
    const float* lw     = (const float*)d_in[2];
    const float* lb     = (const float*)d_in[3];
    const float* w1s    = (const float*)d_in[4];
    const float* b1s    = (const float*)d_in[5];
    const float* w2s    = (const float*)d_in[6];
    const float* b2s    = (const float*)d_in[7];
    const float* temps  = (const float*)d_in[8];
    const float* sigmas = (const float*)d_in[9];

    char* ws = (char*)d_ws;
    const size_t Q_BYTES  = (size_t)BATCH * HW * QC * sizeof(__half);  // 25,690,112
    const size_t F_BYTES  = (size_t)BATCH * 3 * HW * sizeof(float);    //  4,816,896
    float4* q4 = (float4*)ws;
    float* hrA = (float*)(ws + Q_BYTES);
    float* hrB = (float*)(ws + Q_BYTES + F_BYTES);
    float* f0  = (float*)(ws + Q_BYTES + 2 * F_BYTES);                 // 31,104 B

    linear_kernel<<<1944, 256, 0, stream>>>(x, lw, lb, f0);
    bicubic_kernel<<<(BATCH * 3 * HW + 255) / 256, 256, 0, stream>>>(f0, hrA);

    dim3 jgrid(14, 14, BATCH), jblock(TILE, TILE);
    const float* hins[4]  = { hrA, hrB, hrA, hrB };
    float*       fouts[4] = { hrB, hrA, hrB, (float*)d_out };
    for (int s = 0; s < 4; s++) {
        rangeproj_kernel<<<(BATCH * HW) / 256, 256, 0, stream>>>(
            guid, w1s + s * 96, b1s + s * 32, w2s + s * 1024, b2s + s * 32, q4);
        jbu_kernel<<<jgrid, jblock, 0, stream>>>(
            q4, hins[s], fouts[s], temps, sigmas, s);
    }
}

// Round 5
// 376.012 us; speedup vs baseline: 1.4244x; 1.1224x over previous
//
#include <hip/hip_runtime.h>
#include <hip/hip_fp16.h>
#include <math.h>

#define GHH 224
#define GWW 224
#define HW (GHH*GWW)     // 50176
#define BATCH 8
#define RAD 3
#define DIAM 7
#define NPTS 49
#define QC 32
#define TILE 16
#define TP (TILE + 2*RAD)   // 22
#define TPIX (TP*TP)        // 484
#define CS 485              // chunk-plane stride in float4 (pad: 485 % 8 = 5 -> distinct bank-quads)

typedef _Float16 h2 __attribute__((ext_vector_type(2)));

#if defined(__has_builtin)
#if __has_builtin(__builtin_amdgcn_fdot2)
#define HAS_FDOT2 1
#endif
#endif

__device__ __forceinline__ h2 as_h2(float f) { union { float f; h2 h; } u; u.f = f; return u.h; }

__device__ __forceinline__ float dot2acc(float a, float b, float acc) {
#ifdef HAS_FDOT2
    return __builtin_amdgcn_fdot2(as_h2(a), as_h2(b), acc, false);
#else
    union { float f; __half2 h; } ua, ub; ua.f = a; ub.f = b;
    float2 fa = __half22float2(ua.h), fb = __half22float2(ub.h);
    return acc + fa.x * fb.x + fa.y * fb.y;
#endif
}

__device__ __forceinline__ float dot16(const float4& a, const float4& b, float acc) {
    acc = dot2acc(a.x, b.x, acc);
    acc = dot2acc(a.y, b.y, acc);
    acc = dot2acc(a.z, b.z, acc);
    acc = dot2acc(a.w, b.w, acc);
    return acc;
}

__device__ __forceinline__ int refl(int i) {
    if (i < 0) i = -i;
    if (i >= GHH) i = 2 * GHH - 2 - i;
    return i;
}

__device__ __forceinline__ float gelu_fast(float v) {
    float u = 0.7978845608f * v * (1.f + 0.044715f * v * v);
    float e = __expf(2.f * u);
    float th = 1.f - 2.f / (e + 1.f);
    return 0.5f * v * (1.f + th);
}

// ---------------- linear ----------------
__global__ void linear_kernel(const float* __restrict__ x,
                              const float* __restrict__ W,
                              const float* __restrict__ bias,
                              float* __restrict__ f0) {
    int gwave = (blockIdx.x * blockDim.x + threadIdx.x) >> 6;
    int lane = threadIdx.x & 63;
    if (gwave >= BATCH * 972) return;
    int b = gwave / 972, j = gwave % 972;
    const float* xr = x + b * 1000;
    const float* wr = W + j * 1000;
    float s = 0.f;
    for (int k = lane; k < 1000; k += 64)
        s += xr[k] * wr[k];
    #pragma unroll
    for (int off = 32; off; off >>= 1) s += __shfl_down(s, off, 64);
    if (lane == 0) f0[gwave] = s + bias[j];
}

// ---------------- bicubic 18 -> 224 ----------------
__device__ __forceinline__ float cubicw(float d) {
    d = fabsf(d);
    if (d <= 1.f) return ((1.25f * d - 2.25f) * d) * d + 1.f;
    if (d < 2.f)  return ((-0.75f * d + 3.75f) * d - 6.f) * d + 3.f;
    return 0.f;
}

__global__ void bicubic_kernel(const float* __restrict__ f0, float* __restrict__ hr) {
    int idx = blockIdx.x * blockDim.x + threadIdx.x;
    if (idx >= BATCH * 3 * HW) return;
    int w = idx % GWW;
    int h = (idx / GWW) % GHH;
    int bc = idx / HW;
    const float* src = f0 + bc * 18 * 18;
    float xx = (w + 0.5f) * (18.f / 224.f) - 0.5f;
    float yy = (h + 0.5f) * (18.f / 224.f) - 0.5f;
    float fx0 = floorf(xx), fy0 = floorf(yy);
    int x0 = (int)fx0, y0 = (int)fy0;
    float tx = xx - fx0, ty = yy - fy0;
    float wx[4], wy[4];
    int ix[4], iy[4];
    #pragma unroll
    for (int k = 0; k < 4; k++) {
        wx[k] = cubicw(tx - (float)(k - 1));
        wy[k] = cubicw(ty - (float)(k - 1));
        int a = x0 + (k - 1); ix[k] = min(max(a, 0), 17);
        a = y0 + (k - 1);     iy[k] = min(max(a, 0), 17);
    }
    float acc = 0.f;
    #pragma unroll
    for (int ky = 0; ky < 4; ky++) {
        float rowv = 0.f;
        #pragma unroll
        for (int kx = 0; kx < 4; kx++) rowv += wx[kx] * src[iy[ky] * 18 + ix[kx]];
        acc += wy[ky] * rowv;
    }
    hr[idx] = acc;
}

// ---------------- range_proj -> f16 q; weights via SGPR (uniform global indices) ----------------
__global__ __launch_bounds__(256) void rangeproj_kernel(
    const float* __restrict__ guid,
    const float* __restrict__ w1, const float* __restrict__ b1,
    const float* __restrict__ w2, const float* __restrict__ b2,
    float4* __restrict__ q4) {
    __shared__ __align__(16) float4 sout[256 * 5];  // transpose buffer for coalesced stores
    int tid = threadIdx.x;
    int idx = blockIdx.x * 256 + tid;               // grid == BATCH*HW/256 exactly
    int b = idx / HW, pix = idx % HW;
    float g0 = guid[(b * 3 + 0) * HW + pix];
    float g1 = guid[(b * 3 + 1) * HW + pix];
    float g2 = guid[(b * 3 + 2) * HW + pix];
    float h1[QC];
    #pragma unroll
    for (int k = 0; k < QC; k++) {
        float v = w1[k * 3] * g0 + w1[k * 3 + 1] * g1 + w1[k * 3 + 2] * g2 + b1[k];
        h1[k] = gelu_fast(v);
    }
    float4 packv[4];
    float* packf = (float*)packv;
    #pragma unroll
    for (int k = 0; k < QC; k += 2) {
        float a0 = b2[k], a1 = b2[k + 1];
        #pragma unroll
        for (int c = 0; c < QC; c++) {
            a0 += w2[k * QC + c] * h1[c];
            a1 += w2[(k + 1) * QC + c] * h1[c];
        }
        union { __half2 h; float f; } u;
        u.h = __floats2half2_rn(a0, a1);
        packf[k >> 1] = u.f;
    }
    #pragma unroll
    for (int j = 0; j < 4; j++) sout[tid * 5 + j] = packv[j];
    __syncthreads();
    size_t gbase = (size_t)blockIdx.x * 1024;
    #pragma unroll
    for (int k2 = 0; k2 < 4; k2++) {
        int t = k2 * 256 + tid;
        q4[gbase + t] = sout[(t >> 2) * 5 + (t & 3)];
    }
}

// ---------------- fused JBU ----------------
__global__ __launch_bounds__(256, 4) void jbu_kernel(
    const float4* __restrict__ q4,
    const float* __restrict__ hr,
    float* __restrict__ outF,
    const float* __restrict__ temps,
    const float* __restrict__ sigmas,
    int stage)
{
    __shared__ __align__(16) float4 sq[4 * CS];   // 31040 B, q tile chunk-planar (padded stride)
    __shared__ __align__(16) float4 sh[TPIX];     //  7744 B, hr tile (3ch + pad)
    int tx = threadIdx.x, ty = threadIdx.y;
    int tid = ty * TILE + tx;
    int b = blockIdx.z;
    int h0 = blockIdx.y * TILE, w0 = blockIdx.x * TILE;

    bool interior = (h0 >= RAD) && (h0 + TILE + RAD <= GHH) &&
                    (w0 >= RAD) && (w0 + TILE + RAD <= GWW);

    if (interior) {
        const float4* qb = q4 + ((size_t)(b * HW + (h0 - RAD) * GWW + (w0 - RAD))) * 4;
        for (int i = tid; i < 4 * TPIX; i += 256) {
            int px = i >> 2, c = i & 3;
            int r = px / TP, cc = px % TP;
            sq[c * CS + px] = qb[((size_t)r * GWW + cc) * 4 + c];
        }
        const float* hb = hr + (size_t)b * 3 * HW + (size_t)(h0 - RAD) * GWW + (w0 - RAD);
        for (int i = tid; i < TPIX; i += 256) {
            int r = i / TP, cx = i % TP;
            size_t base = (size_t)r * GWW + cx;
            sh[i] = make_float4(hb[base], hb[base + HW], hb[base + 2 * HW], 0.f);
        }
    } else {
        for (int i = tid; i < 4 * TPIX; i += 256) {
            int px = i >> 2, c = i & 3;
            int r = px / TP, cc = px % TP;
            int gh = refl(h0 - RAD + r);
            int gw = refl(w0 - RAD + cc);
            sq[c * CS + px] = q4[(size_t)(b * HW + gh * GWW + gw) * 4 + c];
        }
        for (int i = tid; i < TPIX; i += 256) {
            int r = i / TP, cx = i % TP;
            int gh = refl(h0 - RAD + r);
            int gw = refl(w0 - RAD + cx);
            size_t base = (size_t)b * 3 * HW + (size_t)gh * GWW + gw;
            sh[i] = make_float4(hr[base], hr[base + HW], hr[base + 2 * HW], 0.f);
        }
    }
    __syncthreads();

    int ci = (ty + RAD) * TP + tx + RAD;
    float4 c0 = sq[ci], c1 = sq[CS + ci], c2 = sq[2 * CS + ci], c3 = sq[3 * CS + ci];

    float s[NPTS];
    int p = 0;
    #pragma unroll
    for (int di = 0; di < DIAM; di++) {
        int rb = (ty + di) * TP + tx;
        #pragma unroll
        for (int dj = 0; dj < DIAM; dj++, p++) {
            int ni = rb + dj;
            float acc = dot16(c0, sq[ni], 0.f);
            acc = dot16(c1, sq[CS + ni], acc);
            acc = dot16(c2, sq[2 * CS + ni], acc);
            acc = dot16(c3, sq[3 * CS + ni], acc);
            s[p] = acc;
        }
    }

    // ---- softmax * spatial, renormalize ----
    float t = __expf(temps[stage]);
    t = fminf(fmaxf(t, 1e-4f), 1e4f);
    float sig = sigmas[stage];
    float inv2s2 = 1.f / (2.f * sig * sig);
    float m = -1e30f;
    #pragma unroll
    for (int p2 = 0; p2 < NPTS; p2++) { s[p2] *= t; m = fmaxf(m, s[p2]); }
    float den = 0.f;
    #pragma unroll
    for (int p2 = 0; p2 < NPTS; p2++) { s[p2] = __expf(s[p2] - m); den += s[p2]; }
    float rden = 1.f / den;
    float ksum = 0.f;
    #pragma unroll
    for (int p2 = 0; p2 < NPTS; p2++) {
        int di = p2 / 7, dj = p2 % 7;
        float dy = (float)(di - 3) * (1.f / 3.f);
        float dx = (float)(dj - 3) * (1.f / 3.f);
        float spat = __expf(-(dy * dy + dx * dx) * inv2s2);
        s[p2] = s[p2] * rden * spat;
        ksum += s[p2];
    }
    float rk = 1.f / fmaxf(ksum, 1e-7f);

    // ---- adaptive conv from sh (no barrier needed; sh untouched since stage) ----
    float o0 = 0.f, o1 = 0.f, o2 = 0.f;
    p = 0;
    #pragma unroll
    for (int di = 0; di < DIAM; di++) {
        int rb = (ty + di) * TP + tx;
        #pragma unroll
        for (int dj = 0; dj < DIAM; dj++, p++) {
            float4 hv = sh[rb + dj];
            float kp = s[p] * rk;
            o0 += kp * hv.x;
            o1 += kp * hv.y;
            o2 += kp * hv.z;
        }
    }
    size_t obase = (size_t)b * 3 * HW + (size_t)(h0 + ty) * GWW + (w0 + tx);
    outF[obase]          = o0;
    outF[obase + HW]     = o1;
    outF[obase + 2 * HW] = o2;
}

extern "C" void kernel_launch(void* const* d_in, const int* in_sizes, int n_in,
                              void* d_out, int out_size, void* d_ws, size_t ws_size,
                              hipStream_t stream) {
    const float* x      = (const float*)d_in[0];
    const float* guid   = (const float*)d_in[1];
    const float* lw     = (const float*)d_in[2];
    const float* lb     = (const float*)d_in[3];
    const float* w1s    = (const float*)d_in[4];
    const float* b1s    = (const float*)d_in[5];
    const float* w2s    = (const float*)d_in[6];
    const float* b2s    = (const float*)d_in[7];
    const float* temps  = (const float*)d_in[8];
    const float* sigmas = (const float*)d_in[9];

    char* ws = (char*)d_ws;
    const size_t Q_BYTES  = (size_t)BATCH * HW * QC * sizeof(__half);  // 25,690,112
    const size_t F_BYTES  = (size_t)BATCH * 3 * HW * sizeof(float);    //  4,816,896
    float4* q4 = (float4*)ws;
    float* hrA = (float*)(ws + Q_BYTES);
    float* hrB = (float*)(ws + Q_BYTES + F_BYTES);
    float* f0  = (float*)(ws + Q_BYTES + 2 * F_BYTES);

    linear_kernel<<<1944, 256, 0, stream>>>(x, lw, lb, f0);
    bicubic_kernel<<<(BATCH * 3 * HW + 255) / 256, 256, 0, stream>>>(f0, hrA);

    dim3 jgrid(14, 14, BATCH), jblock(TILE, TILE);
    const float* hins[4]  = { hrA, hrB, hrA, hrB };
    float*       fouts[4] = { hrB, hrA, hrB, (float*)d_out };
    for (int s = 0; s < 4; s++) {
        rangeproj_kernel<<<(BATCH * HW) / 256, 256, 0, stream>>>(
            guid, w1s + s * 96, b1s + s * 32, w2s + s * 1024, b2s + s * 32, q4);
        jbu_kernel<<<jgrid, jblock, 0, stream>>>(
            q4, hins[s], fouts[s], temps, sigmas, s);
    }
}